// Round 11
// baseline (456.397 us; speedup 1.0000x reference)
//
#include <hip/hip_runtime.h>

#define N_NODES 50000
#define N_EDGES 800000
#define DFEAT 64
#define HID 128
#define NBKT 16
#define NPB1 3200         // nodes per coarse bucket = 50*64 -> sub id = dst>>6
#define CAP_C 57344       // coarse capacity: mean 51200, sigma ~219 -> +28 sigma; 56*1024
#define NRCH 56           // refine chunks per coarse bucket (56*1024 = CAP_C)
#define SUBB 50           // sub-buckets per coarse bucket
#define NSUB 800          // 16*50 slots; only ceil(50000/64)=782 used
#define CAP_S 1536        // sub capacity: mean 1024, sigma 32 -> +16 sigma
#define ASTR 65           // LDS acc stride: atomics & b128 reads <=2-way (free)

#define XB_BLOCKS 3125    // N_NODES*DFEAT/4 / 256
#define WB_BLOCKS 16      // HID*2*DFEAT/4 / 256
#define EB_BLOCKS 782     // ceil(N_EDGES/4/256)

typedef __bf16 bf16x8 __attribute__((ext_vector_type(8)));
typedef float f32x4 __attribute__((ext_vector_type(4)));

__device__ inline unsigned short f2bf(float f) {   // round-to-nearest-even
  unsigned u = __float_as_uint(f);
  return (unsigned short)((u + 0x7FFFu + ((u >> 16) & 1u)) >> 16);
}
__device__ inline float bf2f(unsigned short h) {
  return __uint_as_float(((unsigned)h) << 16);
}

// ---------- prep: bf16 convert (x,W) + coarse bin by dst/3200 ----------
__global__ __launch_bounds__(256) void k_prep(const float* __restrict__ x,
                                              const float* __restrict__ W,
                                              const int* __restrict__ ei,
                                              unsigned short* __restrict__ xb,
                                              unsigned short* __restrict__ Wb,
                                              int* __restrict__ ccnt,
                                              unsigned int* __restrict__ coarse) {
  int bid = blockIdx.x;
  if (bid < XB_BLOCKS) {                      // x -> bf16
    int t = bid * 256 + threadIdx.x;
    float4 v = *(const float4*)&x[t * 4];
    ushort4 o = {f2bf(v.x), f2bf(v.y), f2bf(v.z), f2bf(v.w)};
    *(ushort4*)&xb[t * 4] = o;
    return;
  }
  bid -= XB_BLOCKS;
  if (bid < WB_BLOCKS) {                      // W -> bf16
    int t = bid * 256 + threadIdx.x;
    float4 v = *(const float4*)&W[t * 4];
    ushort4 o = {f2bf(v.x), f2bf(v.y), f2bf(v.z), f2bf(v.w)};
    *(ushort4*)&Wb[t * 4] = o;
    return;
  }
  bid -= WB_BLOCKS;
  // coarse binning: 1024 edges per block, LDS hist + contiguous packed writes
  __shared__ int lcnt[NBKT];
  __shared__ int lbase[NBKT];
  const int tid = threadIdx.x;
  if (tid < NBKT) lcnt[tid] = 0;
  __syncthreads();

  int e0 = (bid * 256 + tid) * 4;
  bool valid = e0 < N_EDGES;                  // N_EDGES%4==0: all-or-nothing
  int bkt[4], rank[4];
  unsigned int pk[4];
  if (valid) {
    int4 s4 = *(const int4*)&ei[e0];
    int4 d4 = *(const int4*)&ei[N_EDGES + e0];
    int ss[4] = {s4.x, s4.y, s4.z, s4.w};
    int dd[4] = {d4.x, d4.y, d4.z, d4.w};
#pragma unroll
    for (int i = 0; i < 4; ++i) {
      bkt[i] = dd[i] / NPB1;                  // magic-mul
      pk[i] = ((unsigned)dd[i] << 16) | (unsigned)ss[i];
    }
#pragma unroll
    for (int i = 0; i < 4; ++i) rank[i] = atomicAdd(&lcnt[bkt[i]], 1);
  }
  __syncthreads();
  if (tid < NBKT) lbase[tid] = atomicAdd(&ccnt[tid], lcnt[tid]);
  __syncthreads();
  if (valid) {
#pragma unroll
    for (int i = 0; i < 4; ++i) {
      int pos = lbase[bkt[i]] + rank[i];
      if (pos < CAP_C) coarse[bkt[i] * CAP_C + pos] = pk[i];
    }
  }
}

// ---------- refine: coarse bucket -> 50 sub-buckets of 64 nodes each ----------
// 1024 edges per block; ~45K global atomics total (vs 800K per-node before);
// writes land in ~80B contiguous runs per sub-bucket region.
__global__ __launch_bounds__(256) void k_refine(const unsigned int* __restrict__ coarse,
                                                const int* __restrict__ ccnt,
                                                int* __restrict__ subcnt,
                                                unsigned int* __restrict__ sub) {
  __shared__ int lcnt[SUBB];
  __shared__ int lbase[SUBB];
  const int tid = threadIdx.x;
  const int b = blockIdx.x / NRCH;      // coarse bucket 0..15
  const int c = blockIdx.x % NRCH;      // chunk within bucket

  if (tid < SUBB) lcnt[tid] = 0;
  __syncthreads();

  int cnt = ccnt[b];
  cnt = cnt < CAP_C ? cnt : CAP_C;
  const unsigned int* cb = &coarse[(size_t)b * CAP_C];
  int idx0 = c * 1024 + tid * 4;

  unsigned p[4];
  int sl[4], rk[4];
  bool v[4];
#pragma unroll
  for (int i = 0; i < 4; ++i) {
    v[i] = (idx0 + i) < cnt;
    p[i] = v[i] ? cb[idx0 + i] : 0u;
  }
#pragma unroll
  for (int i = 0; i < 4; ++i) {
    if (v[i]) {
      int d = (int)(p[i] >> 16);
      sl[i] = (d >> 6) - b * SUBB;      // local sub-bucket 0..49
      rk[i] = atomicAdd(&lcnt[sl[i]], 1);
    }
  }
  __syncthreads();
  if (tid < SUBB) lbase[tid] = atomicAdd(&subcnt[b * SUBB + tid], lcnt[tid]);
  __syncthreads();
#pragma unroll
  for (int i = 0; i < 4; ++i) {
    if (v[i]) {
      int d = (int)(p[i] >> 16);
      int pos = lbase[sl[i]] + rk[i];
      if (pos < CAP_S)
        sub[(size_t)(b * SUBB + sl[i]) * CAP_S + pos] =
            ((unsigned)(d & 63) << 16) | (p[i] & 0xffffu);
    }
  }
}

// ---------- fused pull + MFMA fc: block = sub-bucket = 64 nodes ----------
__global__ __launch_bounds__(256) void k_pullfc(const unsigned short* __restrict__ xb,
                                                const unsigned short* __restrict__ Wb,
                                                const int* __restrict__ subcnt,
                                                const unsigned int* __restrict__ sub,
                                                const float* __restrict__ bv,
                                                float* __restrict__ out) {
  __shared__ float acc[64 * ASTR];      // 16.6 KB fp32 neighbor sums
  __shared__ unsigned int q[CAP_S];     // 6 KB staged edge queue

  const int tid = threadIdx.x;
  const int sb = blockIdx.x;            // sub-bucket id = node>>6
  const int nb = sb * 64;
  const int wave = tid >> 6;
  const int lane = tid & 63;

  for (int i = tid; i < 64 * ASTR; i += 256) acc[i] = 0.f;

  int cnt = subcnt[sb];
  cnt = cnt < CAP_S ? cnt : CAP_S;
  const unsigned int* qb = &sub[(size_t)sb * CAP_S];
  for (int i = tid; i < cnt; i += 256) q[i] = qb[i];   // coalesced stage
  __syncthreads();

  // entry-parallel gather: wave takes 8 entries per iter (ILP-8), lane = feature
  for (int i = wave * 8; i < cnt; i += 32) {
    int rem = cnt - i;
    int m = rem < 8 ? rem : 8;
    unsigned e[8];
    float val[8];
#pragma unroll
    for (int k = 0; k < 8; ++k) e[k] = (k < m) ? q[i + k] : q[i];
#pragma unroll
    for (int k = 0; k < 8; ++k)
      val[k] = bf2f(xb[(e[k] & 0xffffu) * DFEAT + lane]);
#pragma unroll
    for (int k = 0; k < 8; ++k)
      if (k < m) atomicAdd(&acc[(e[k] >> 16) * ASTR + lane], val[k]);
  }
  __syncthreads();

  // fc: wave = 16 nodes x 128 outs via mfma 16x16x32 bf16
  const int l15 = lane & 15;
  const int quad = lane >> 4;
  const int node0 = nb + wave * 16;

  int anode = node0 + l15;
  if (anode >= N_NODES) anode = N_NODES - 1;   // clamp; stores guarded
  const unsigned short* hx = xb + (size_t)anode * DFEAT;

  bf16x8 fa0 = *(const bf16x8*)(hx + quad * 8);        // k 0..31
  bf16x8 fa1 = *(const bf16x8*)(hx + 32 + quad * 8);   // k 32..63
  bf16x8 fa2, fa3;                                     // k 64..127 from LDS acc
  {
    const float* ar = &acc[(wave * 16 + l15) * ASTR];
#pragma unroll
    for (int j = 0; j < 8; ++j) {
      fa2[j] = (__bf16)ar[quad * 8 + j];
      fa3[j] = (__bf16)ar[32 + quad * 8 + j];
    }
  }

  f32x4 accr[8];
#pragma unroll
  for (int nt = 0; nt < 8; ++nt) accr[nt] = (f32x4){0.f, 0.f, 0.f, 0.f};

#pragma unroll
  for (int nt = 0; nt < 8; ++nt) {
    const unsigned short* wr = Wb + (size_t)(nt * 16 + l15) * (2 * DFEAT) + quad * 8;
    bf16x8 b0 = *(const bf16x8*)(wr);
    bf16x8 b1 = *(const bf16x8*)(wr + 32);
    bf16x8 b2 = *(const bf16x8*)(wr + 64);
    bf16x8 b3 = *(const bf16x8*)(wr + 96);
    accr[nt] = __builtin_amdgcn_mfma_f32_16x16x32_bf16(fa0, b0, accr[nt], 0, 0, 0);
    accr[nt] = __builtin_amdgcn_mfma_f32_16x16x32_bf16(fa1, b1, accr[nt], 0, 0, 0);
    accr[nt] = __builtin_amdgcn_mfma_f32_16x16x32_bf16(fa2, b2, accr[nt], 0, 0, 0);
    accr[nt] = __builtin_amdgcn_mfma_f32_16x16x32_bf16(fa3, b3, accr[nt], 0, 0, 0);
  }

  // epilogue: D[m=quad*4+r][n=nt*16+l15]
#pragma unroll
  for (int nt = 0; nt < 8; ++nt) {
    float bias = bv[nt * 16 + l15];
#pragma unroll
    for (int r = 0; r < 4; ++r) {
      int node = node0 + quad * 4 + r;
      if (node < N_NODES) {
        float v = accr[nt][r] + bias;
        out[(size_t)node * HID + nt * 16 + l15] = v > 0.f ? v : 0.f;
      }
    }
  }
}

extern "C" void kernel_launch(void* const* d_in, const int* in_sizes, int n_in,
                              void* d_out, int out_size, void* d_ws, size_t ws_size,
                              hipStream_t stream) {
  const float* x = (const float*)d_in[0];
  const int* ei = (const int*)d_in[1];
  const float* W = (const float*)d_in[2];
  const float* b = (const float*)d_in[3];
  float* out = (float*)d_out;

  // workspace layout (~15 MB), 256B-aligned regions
  char* ws = (char*)d_ws;
  int* ccnt            = (int*)ws;            ws += 256;                       // 16 ints
  int* subcnt          = (int*)ws;            ws += ((size_t)NSUB * 4 + 255) / 256 * 256;
  unsigned int* coarse = (unsigned int*)ws;   ws += (size_t)NBKT * CAP_C * 4;
  unsigned int* sub    = (unsigned int*)ws;   ws += (size_t)NSUB * CAP_S * 4;
  unsigned short* xb   = (unsigned short*)ws; ws += (size_t)N_NODES * DFEAT * 2;
  unsigned short* Wb   = (unsigned short*)ws; ws += (size_t)HID * 2 * DFEAT * 2;

  // zero ccnt + subcnt (contiguous padded regions)
  hipMemsetAsync(ccnt, 0, 256 + ((size_t)NSUB * 4 + 255) / 256 * 256, stream);

  k_prep<<<XB_BLOCKS + WB_BLOCKS + EB_BLOCKS, 256, 0, stream>>>(
      x, W, ei, xb, Wb, ccnt, coarse);
  k_refine<<<NBKT * NRCH, 256, 0, stream>>>(coarse, ccnt, subcnt, sub);
  k_pullfc<<<(N_NODES + 63) / 64, 256, 0, stream>>>(xb, Wb, subcnt, sub, b, out);
}

// Round 12
// 138.517 us; speedup vs baseline: 3.2949x; 3.2949x over previous
//
#include <hip/hip_runtime.h>

#define N_NODES 50000
#define N_EDGES 800000
#define DFEAT 64
#define HID 128
#define NBKT 16
#define NPB1 3200         // nodes per coarse bucket = 50*64 -> sub id = dst>>6
#define CAP_C 57344       // coarse capacity: mean 51200, sigma ~219 -> +28 sigma
#define NRCH 56           // refine chunks per coarse bucket (56*1024 = CAP_C)
#define SUBB 50           // sub-buckets per coarse bucket
#define NSUB 800          // 16*50 slots; only 782 used
#define CAP_S 1536        // sub capacity: mean 1024, sigma 32 -> +16 sigma

#define XB_BLOCKS 3125    // N_NODES*DFEAT/4 / 256
#define WB_BLOCKS 16      // HID*2*DFEAT/4 / 256
#define EB_BLOCKS 782     // ceil(N_EDGES/4/256)

typedef __bf16 bf16x8 __attribute__((ext_vector_type(8)));
typedef float f32x4 __attribute__((ext_vector_type(4)));

__device__ inline unsigned short f2bf(float f) {   // round-to-nearest-even
  unsigned u = __float_as_uint(f);
  return (unsigned short)((u + 0x7FFFu + ((u >> 16) & 1u)) >> 16);
}
__device__ inline float bf2f(unsigned short h) {
  return __uint_as_float(((unsigned)h) << 16);
}

// ---------- prep: bf16 convert (x,W) + coarse bin by dst/3200 ----------
__global__ __launch_bounds__(256) void k_prep(const float* __restrict__ x,
                                              const float* __restrict__ W,
                                              const int* __restrict__ ei,
                                              unsigned short* __restrict__ xb,
                                              unsigned short* __restrict__ Wb,
                                              int* __restrict__ ccnt,
                                              unsigned int* __restrict__ coarse) {
  int bid = blockIdx.x;
  if (bid < XB_BLOCKS) {                      // x -> bf16
    int t = bid * 256 + threadIdx.x;
    float4 v = *(const float4*)&x[t * 4];
    ushort4 o = {f2bf(v.x), f2bf(v.y), f2bf(v.z), f2bf(v.w)};
    *(ushort4*)&xb[t * 4] = o;
    return;
  }
  bid -= XB_BLOCKS;
  if (bid < WB_BLOCKS) {                      // W -> bf16
    int t = bid * 256 + threadIdx.x;
    float4 v = *(const float4*)&W[t * 4];
    ushort4 o = {f2bf(v.x), f2bf(v.y), f2bf(v.z), f2bf(v.w)};
    *(ushort4*)&Wb[t * 4] = o;
    return;
  }
  bid -= WB_BLOCKS;
  // coarse binning: 1024 edges per block, LDS hist + contiguous packed writes
  __shared__ int lcnt[NBKT];
  __shared__ int lbase[NBKT];
  const int tid = threadIdx.x;
  if (tid < NBKT) lcnt[tid] = 0;
  __syncthreads();

  int e0 = (bid * 256 + tid) * 4;
  bool valid = e0 < N_EDGES;                  // N_EDGES%4==0: all-or-nothing
  int bkt[4], rank[4];
  unsigned int pk[4];
  if (valid) {
    int4 s4 = *(const int4*)&ei[e0];
    int4 d4 = *(const int4*)&ei[N_EDGES + e0];
    int ss[4] = {s4.x, s4.y, s4.z, s4.w};
    int dd[4] = {d4.x, d4.y, d4.z, d4.w};
#pragma unroll
    for (int i = 0; i < 4; ++i) {
      bkt[i] = dd[i] / NPB1;                  // magic-mul
      pk[i] = ((unsigned)dd[i] << 16) | (unsigned)ss[i];
    }
#pragma unroll
    for (int i = 0; i < 4; ++i) rank[i] = atomicAdd(&lcnt[bkt[i]], 1);
  }
  __syncthreads();
  if (tid < NBKT) lbase[tid] = atomicAdd(&ccnt[tid], lcnt[tid]);
  __syncthreads();
  if (valid) {
#pragma unroll
    for (int i = 0; i < 4; ++i) {
      int pos = lbase[bkt[i]] + rank[i];
      if (pos < CAP_C) coarse[bkt[i] * CAP_C + pos] = pk[i];
    }
  }
}

// ---------- refine: coarse bucket -> 50 sub-buckets of 64 nodes each ----------
__global__ __launch_bounds__(256) void k_refine(const unsigned int* __restrict__ coarse,
                                                const int* __restrict__ ccnt,
                                                int* __restrict__ subcnt,
                                                unsigned int* __restrict__ sub) {
  __shared__ int lcnt[SUBB];
  __shared__ int lbase[SUBB];
  const int tid = threadIdx.x;
  const int b = blockIdx.x / NRCH;      // coarse bucket 0..15
  const int c = blockIdx.x % NRCH;      // chunk within bucket

  if (tid < SUBB) lcnt[tid] = 0;
  __syncthreads();

  int cnt = ccnt[b];
  cnt = cnt < CAP_C ? cnt : CAP_C;
  const unsigned int* cb = &coarse[(size_t)b * CAP_C];
  int idx0 = c * 1024 + tid * 4;

  unsigned p[4];
  int sl[4], rk[4];
  bool v[4];
#pragma unroll
  for (int i = 0; i < 4; ++i) {
    v[i] = (idx0 + i) < cnt;
    p[i] = v[i] ? cb[idx0 + i] : 0u;
  }
#pragma unroll
  for (int i = 0; i < 4; ++i) {
    if (v[i]) {
      int d = (int)(p[i] >> 16);
      sl[i] = (d >> 6) - b * SUBB;      // local sub-bucket 0..49
      rk[i] = atomicAdd(&lcnt[sl[i]], 1);
    }
  }
  __syncthreads();
  if (tid < SUBB) lbase[tid] = atomicAdd(&subcnt[b * SUBB + tid], lcnt[tid]);
  __syncthreads();
#pragma unroll
  for (int i = 0; i < 4; ++i) {
    if (v[i]) {
      int d = (int)(p[i] >> 16);
      int pos = lbase[sl[i]] + rk[i];
      if (pos < CAP_S)
        sub[(size_t)(b * SUBB + sl[i]) * CAP_S + pos] =
            ((unsigned)(d & 63) << 16) | (p[i] & 0xffffu);
    }
  }
}

// ---------- pull: LDS counting-sort by node, wave-per-node uint gather ----------
// Block = 1024 threads (16 waves) = one sub-bucket of 64 nodes; wave handles 4
// nodes; per load round lane covers (entry-half, feature-pair) -> 2 entries x
// 64 feats per instruction; no FP atomics anywhere.
__global__ __launch_bounds__(1024) void k_pullsub(const unsigned short* __restrict__ xb,
                                                  const int* __restrict__ subcnt,
                                                  const unsigned int* __restrict__ sub,
                                                  unsigned short* __restrict__ nbf) {
  __shared__ unsigned int q[CAP_S];
  __shared__ unsigned int sq[CAP_S];
  __shared__ int lcnt[64];
  __shared__ int lbase[65];

  const int tid = threadIdx.x;
  const int sb = blockIdx.x;
  const int nb = sb * 64;

  if (tid < 64) lcnt[tid] = 0;

  int cnt = subcnt[sb];
  cnt = cnt < CAP_S ? cnt : CAP_S;
  const unsigned int* qb = &sub[(size_t)sb * CAP_S];
  for (int i = tid; i < cnt; i += 1024) q[i] = qb[i];
  __syncthreads();

  // pass 1: rank within node (int LDS atomics, cheap)
  int myrank[2], myidx[2], nloc = 0;
  for (int i = tid; i < cnt; i += 1024) {
    int rel = (int)(q[i] >> 16);
    myrank[nloc] = atomicAdd(&lcnt[rel], 1);
    myidx[nloc] = i;
    ++nloc;
  }
  __syncthreads();
  // scan of 64 counts by wave 0
  if (tid < 64) {
    int v = lcnt[tid];
    int inc = v;
#pragma unroll
    for (int o = 1; o < 64; o <<= 1) {
      int u = __shfl_up(inc, o);
      if (tid >= o) inc += u;
    }
    lbase[tid] = inc - v;
    if (tid == 63) lbase[64] = inc;
  }
  __syncthreads();
  // pass 2: scatter into sorted order
  for (int k = 0; k < nloc; ++k) {
    unsigned e = q[myidx[k]];
    sq[lbase[e >> 16] + myrank[k]] = e;
  }
  __syncthreads();

  // accumulate: wave w -> nodes w*4..w*4+3
  const int wave = tid >> 6;
  const int lane = tid & 63;
  const int half = lane >> 5;     // which entry of the pair
  const int l31 = lane & 31;      // uint index = feature pair
  const unsigned int* xu = (const unsigned int*)xb;

#pragma unroll
  for (int i2 = 0; i2 < 4; ++i2) {
    int n = wave * 4 + i2;
    int beg = lbase[n], end = lbase[n + 1];
    float s0x = 0.f, s0y = 0.f, s1x = 0.f, s1y = 0.f,
          s2x = 0.f, s2y = 0.f, s3x = 0.f, s3y = 0.f;
    int j = beg + half;
    for (; j + 6 < end; j += 8) {          // 8 entries per iter (2 halves x ILP4)
      unsigned e0 = sq[j], e1 = sq[j + 2], e2 = sq[j + 4], e3 = sq[j + 6];
      unsigned v0 = xu[(e0 & 0xffffu) * 32 + l31];
      unsigned v1 = xu[(e1 & 0xffffu) * 32 + l31];
      unsigned v2 = xu[(e2 & 0xffffu) * 32 + l31];
      unsigned v3 = xu[(e3 & 0xffffu) * 32 + l31];
      s0x += bf2f((unsigned short)(v0 & 0xffffu)); s0y += bf2f((unsigned short)(v0 >> 16));
      s1x += bf2f((unsigned short)(v1 & 0xffffu)); s1y += bf2f((unsigned short)(v1 >> 16));
      s2x += bf2f((unsigned short)(v2 & 0xffffu)); s2y += bf2f((unsigned short)(v2 >> 16));
      s3x += bf2f((unsigned short)(v3 & 0xffffu)); s3y += bf2f((unsigned short)(v3 >> 16));
    }
    for (; j < end; j += 2) {
      unsigned e = sq[j];
      unsigned v = xu[(e & 0xffffu) * 32 + l31];
      s0x += bf2f((unsigned short)(v & 0xffffu));
      s0y += bf2f((unsigned short)(v >> 16));
    }
    float sx = (s0x + s1x) + (s2x + s3x);
    float sy = (s0y + s1y) + (s2y + s3y);
    sx += __shfl_xor(sx, 32);
    sy += __shfl_xor(sy, 32);
    int node = nb + n;
    if (half == 0 && node < N_NODES) {
      unsigned o = (unsigned)f2bf(sx) | ((unsigned)f2bf(sy) << 16);
      ((unsigned int*)nbf)[node * 32 + l31] = o;
    }
  }
}

// ---------- fc via MFMA 16x16x32 bf16, no LDS (R7-verified) ----------
__global__ __launch_bounds__(256) void k_fc(const unsigned short* __restrict__ xb,
                                            const unsigned short* __restrict__ nbf,
                                            const unsigned short* __restrict__ Wb,
                                            const float* __restrict__ bv,
                                            float* __restrict__ out) {
  const int tid = threadIdx.x;
  const int wave = tid >> 6;
  const int lane = tid & 63;
  const int l15 = lane & 15;
  const int quad = lane >> 4;
  const int node0 = blockIdx.x * 64 + wave * 16;

  int anode = node0 + l15;
  if (anode >= N_NODES) anode = N_NODES - 1;   // clamp; stores guarded
  const unsigned short* hx = xb + (size_t)anode * DFEAT;
  const unsigned short* hn = nbf + (size_t)anode * DFEAT;

  bf16x8 a0 = *(const bf16x8*)(hx + quad * 8);
  bf16x8 a1 = *(const bf16x8*)(hx + 32 + quad * 8);
  bf16x8 a2 = *(const bf16x8*)(hn + quad * 8);
  bf16x8 a3 = *(const bf16x8*)(hn + 32 + quad * 8);

  f32x4 acc[8];
#pragma unroll
  for (int nt = 0; nt < 8; ++nt) acc[nt] = (f32x4){0.f, 0.f, 0.f, 0.f};

#pragma unroll
  for (int nt = 0; nt < 8; ++nt) {
    const unsigned short* wr = Wb + (size_t)(nt * 16 + l15) * (2 * DFEAT) + quad * 8;
    bf16x8 b0 = *(const bf16x8*)(wr);
    bf16x8 b1 = *(const bf16x8*)(wr + 32);
    bf16x8 b2 = *(const bf16x8*)(wr + 64);
    bf16x8 b3 = *(const bf16x8*)(wr + 96);
    acc[nt] = __builtin_amdgcn_mfma_f32_16x16x32_bf16(a0, b0, acc[nt], 0, 0, 0);
    acc[nt] = __builtin_amdgcn_mfma_f32_16x16x32_bf16(a1, b1, acc[nt], 0, 0, 0);
    acc[nt] = __builtin_amdgcn_mfma_f32_16x16x32_bf16(a2, b2, acc[nt], 0, 0, 0);
    acc[nt] = __builtin_amdgcn_mfma_f32_16x16x32_bf16(a3, b3, acc[nt], 0, 0, 0);
  }

#pragma unroll
  for (int nt = 0; nt < 8; ++nt) {
    float bias = bv[nt * 16 + l15];
#pragma unroll
    for (int r = 0; r < 4; ++r) {
      int node = node0 + quad * 4 + r;
      if (node < N_NODES) {
        float v = acc[nt][r] + bias;
        out[(size_t)node * HID + nt * 16 + l15] = v > 0.f ? v : 0.f;
      }
    }
  }
}

extern "C" void kernel_launch(void* const* d_in, const int* in_sizes, int n_in,
                              void* d_out, int out_size, void* d_ws, size_t ws_size,
                              hipStream_t stream) {
  const float* x = (const float*)d_in[0];
  const int* ei = (const int*)d_in[1];
  const float* W = (const float*)d_in[2];
  const float* b = (const float*)d_in[3];
  float* out = (float*)d_out;

  // workspace layout (~22 MB), 256B-aligned regions
  char* ws = (char*)d_ws;
  int* ccnt            = (int*)ws;            ws += 256;
  int* subcnt          = (int*)ws;            ws += 3328;   // 800 ints padded
  unsigned int* coarse = (unsigned int*)ws;   ws += (size_t)NBKT * CAP_C * 4;
  unsigned int* sub    = (unsigned int*)ws;   ws += (size_t)NSUB * CAP_S * 4;
  unsigned short* xb   = (unsigned short*)ws; ws += (size_t)N_NODES * DFEAT * 2;
  unsigned short* Wb   = (unsigned short*)ws; ws += (size_t)HID * 2 * DFEAT * 2;
  unsigned short* nbf  = (unsigned short*)ws; ws += (size_t)N_NODES * DFEAT * 2;

  hipMemsetAsync(ccnt, 0, 256 + 3328, stream);   // ccnt + subcnt

  k_prep<<<XB_BLOCKS + WB_BLOCKS + EB_BLOCKS, 256, 0, stream>>>(
      x, W, ei, xb, Wb, ccnt, coarse);
  k_refine<<<NBKT * NRCH, 256, 0, stream>>>(coarse, ccnt, subcnt, sub);
  k_pullsub<<<(N_NODES + 63) / 64, 1024, 0, stream>>>(xb, subcnt, sub, nbf);
  k_fc<<<(N_NODES + 63) / 64, 256, 0, stream>>>(xb, nbf, Wb, b, out);
}

// Round 13
// 127.062 us; speedup vs baseline: 3.5919x; 1.0902x over previous
//
#include <hip/hip_runtime.h>

#define N_NODES 50000
#define N_EDGES 800000
#define DFEAT 64
#define HID 128
#define NBKT 16
#define NPB1 3200         // nodes per coarse bucket = 50*64 -> sub id = dst>>6
#define SLOTS 112         // per (edge-block, bucket) coarse slots: mean 64 +6.2 sigma
#define CAPB (782 * SLOTS)        // coarse bucket stride (87584 entries)
#define SEGS 14           // segments per refine chunk (56*14 = 784 >= 782)
#define NRCH 56           // refine chunks per coarse bucket
#define SUBB 50           // sub-buckets per coarse bucket
#define NSUB 800          // 16*50 slots; 782 used
#define CAP_S 1536        // sub capacity: mean 1024, sigma 32 -> +16 sigma
#define NSTR 66           // ns_u stride: write 2-way, frag read 2-way (free)

#define XB_BLOCKS 3125    // N_NODES*DFEAT/4 / 256
#define WB_BLOCKS 16      // HID*2*DFEAT/4 / 256
#define EB_BLOCKS 782     // ceil(N_EDGES/4/256)

typedef __bf16 bf16x8 __attribute__((ext_vector_type(8)));
typedef float f32x4 __attribute__((ext_vector_type(4)));

__device__ inline unsigned short f2bf(float f) {   // round-to-nearest-even
  unsigned u = __float_as_uint(f);
  return (unsigned short)((u + 0x7FFFu + ((u >> 16) & 1u)) >> 16);
}
__device__ inline float bf2f(unsigned short h) {
  return __uint_as_float(((unsigned)h) << 16);
}

// ---------- prep: bf16 cvt (x,W) + zero subcnt + det-slot coarse bin ----------
__global__ __launch_bounds__(256) void k_prep(const float* __restrict__ x,
                                              const float* __restrict__ W,
                                              const int* __restrict__ ei,
                                              unsigned short* __restrict__ xb,
                                              unsigned short* __restrict__ Wb,
                                              int* __restrict__ subcnt,
                                              int* __restrict__ pcnt,
                                              unsigned int* __restrict__ coarse) {
  int bid = blockIdx.x;
  if (bid < XB_BLOCKS) {                      // x -> bf16
    int t = bid * 256 + threadIdx.x;
    float4 v = *(const float4*)&x[t * 4];
    ushort4 o = {f2bf(v.x), f2bf(v.y), f2bf(v.z), f2bf(v.w)};
    *(ushort4*)&xb[t * 4] = o;
    return;
  }
  bid -= XB_BLOCKS;
  if (bid < WB_BLOCKS) {                      // W -> bf16 (+ zero subcnt: used
    int t = bid * 256 + threadIdx.x;          //  only by NEXT dispatch, safe)
    float4 v = *(const float4*)&W[t * 4];
    ushort4 o = {f2bf(v.x), f2bf(v.y), f2bf(v.z), f2bf(v.w)};
    *(ushort4*)&Wb[t * 4] = o;
    int z = bid * 50 + threadIdx.x;
    if (threadIdx.x < 50 && z < NSUB) subcnt[z] = 0;
    return;
  }
  bid -= WB_BLOCKS;
  // coarse binning: 1024 edges/block, deterministic slot base bid*SLOTS
  __shared__ int lcnt[NBKT];
  const int tid = threadIdx.x;
  if (tid < NBKT) lcnt[tid] = 0;
  __syncthreads();

  int e0 = (bid * 256 + tid) * 4;
  bool valid = e0 < N_EDGES;                  // N_EDGES%4==0: all-or-nothing
  if (valid) {
    int4 s4 = *(const int4*)&ei[e0];
    int4 d4 = *(const int4*)&ei[N_EDGES + e0];
    int ss[4] = {s4.x, s4.y, s4.z, s4.w};
    int dd[4] = {d4.x, d4.y, d4.z, d4.w};
#pragma unroll
    for (int i = 0; i < 4; ++i) {
      int bkt = dd[i] / NPB1;                 // magic-mul
      int rank = atomicAdd(&lcnt[bkt], 1);
      if (rank < SLOTS)
        coarse[(size_t)bkt * CAPB + bid * SLOTS + rank] =
            ((unsigned)dd[i] << 16) | (unsigned)ss[i];
    }
  }
  __syncthreads();
  if (tid < NBKT) {
    int c = lcnt[tid];
    pcnt[bid * NBKT + tid] = c < SLOTS ? c : SLOTS;
  }
}

// ---------- refine: 14 coarse segments -> 50 sub-buckets of 64 nodes ----------
__global__ __launch_bounds__(256) void k_refine(const unsigned int* __restrict__ coarse,
                                                const int* __restrict__ pcnt,
                                                int* __restrict__ subcnt,
                                                unsigned int* __restrict__ sub) {
  __shared__ int lcnt[SUBB];
  __shared__ int lbase[SUBB];
  __shared__ int scnt[SEGS];
  const int tid = threadIdx.x;
  const int b = blockIdx.x / NRCH;      // coarse bucket 0..15
  const int c = blockIdx.x % NRCH;      // chunk: segments c*14..c*14+13

  if (tid < SUBB) lcnt[tid] = 0;
  if (tid < SEGS) {
    int seg = c * SEGS + tid;
    scnt[tid] = (seg < EB_BLOCKS) ? pcnt[seg * NBKT + b] : 0;
  }
  __syncthreads();

  // up to 14*112 = 1568 entries; idx -> (seg, off)
  unsigned p[7];
  int sl[7], rk[7];
  bool v[7];
#pragma unroll
  for (int j = 0; j < 7; ++j) {
    int idx = j * 256 + tid;
    v[j] = false;
    if (idx < SEGS * SLOTS) {
      int seg = idx / SLOTS;
      int off = idx % SLOTS;
      if (off < scnt[seg]) {
        p[j] = coarse[(size_t)b * CAPB + (c * SEGS + seg) * SLOTS + off];
        sl[j] = ((int)(p[j] >> 16) >> 6) - b * SUBB;   // local sub 0..49
        rk[j] = atomicAdd(&lcnt[sl[j]], 1);
        v[j] = true;
      }
    }
  }
  __syncthreads();
  if (tid < SUBB) lbase[tid] = atomicAdd(&subcnt[b * SUBB + tid], lcnt[tid]);
  __syncthreads();
#pragma unroll
  for (int j = 0; j < 7; ++j) {
    if (v[j]) {
      int pos = lbase[sl[j]] + rk[j];
      if (pos < CAP_S)
        sub[(size_t)(b * SUBB + sl[j]) * CAP_S + pos] =
            ((p[j] & 0x3f0000u)) | (p[j] & 0xffffu);   // (d&63)<<16 | src
    }
  }
}

// ---------- fused: counting-sort pull + MFMA fc, block = 64 nodes ----------
__global__ __launch_bounds__(1024) void k_gnn(const unsigned short* __restrict__ xb,
                                              const unsigned short* __restrict__ Wb,
                                              const int* __restrict__ subcnt,
                                              const unsigned int* __restrict__ sub,
                                              const float* __restrict__ bv,
                                              float* __restrict__ out) {
  __shared__ unsigned int q[CAP_S];
  __shared__ unsigned int sq[CAP_S];
  __shared__ unsigned int ns_u[32 * NSTR];   // [feat-pair][node], bf16x2 packed
  __shared__ int lcnt[64];
  __shared__ int lbase[65];

  const int tid = threadIdx.x;
  const int sb = blockIdx.x;
  const int nb = sb * 64;

  if (tid < 64) lcnt[tid] = 0;

  int cnt = subcnt[sb];
  cnt = cnt < CAP_S ? cnt : CAP_S;
  const unsigned int* qb = &sub[(size_t)sb * CAP_S];
  for (int i = tid; i < cnt; i += 1024) q[i] = qb[i];
  __syncthreads();

  // counting sort by node (int LDS atomics only)
  int myrank[2], myidx[2], nloc = 0;
  for (int i = tid; i < cnt; i += 1024) {
    int rel = (int)(q[i] >> 16);
    myrank[nloc] = atomicAdd(&lcnt[rel], 1);
    myidx[nloc] = i;
    ++nloc;
  }
  __syncthreads();
  if (tid < 64) {
    int v = lcnt[tid];
    int inc = v;
#pragma unroll
    for (int o = 1; o < 64; o <<= 1) {
      int u = __shfl_up(inc, o);
      if (tid >= o) inc += u;
    }
    lbase[tid] = inc - v;
    if (tid == 63) lbase[64] = inc;
  }
  __syncthreads();
  for (int k = 0; k < nloc; ++k) {
    unsigned e = q[myidx[k]];
    sq[lbase[e >> 16] + myrank[k]] = e;
  }
  __syncthreads();

  // gather: wave w -> nodes w*4..w*4+3; lane = (entry-half, feature-pair)
  const int wave = tid >> 6;
  const int lane = tid & 63;
  const int half = lane >> 5;
  const int l31 = lane & 31;
  const unsigned int* xu = (const unsigned int*)xb;

#pragma unroll
  for (int i2 = 0; i2 < 4; ++i2) {
    int n = wave * 4 + i2;
    int beg = lbase[n], end = lbase[n + 1];
    float s0x = 0.f, s0y = 0.f, s1x = 0.f, s1y = 0.f,
          s2x = 0.f, s2y = 0.f, s3x = 0.f, s3y = 0.f;
    int j = beg + half;
    for (; j + 6 < end; j += 8) {
      unsigned e0 = sq[j], e1 = sq[j + 2], e2 = sq[j + 4], e3 = sq[j + 6];
      unsigned v0 = xu[(e0 & 0xffffu) * 32 + l31];
      unsigned v1 = xu[(e1 & 0xffffu) * 32 + l31];
      unsigned v2 = xu[(e2 & 0xffffu) * 32 + l31];
      unsigned v3 = xu[(e3 & 0xffffu) * 32 + l31];
      s0x += bf2f((unsigned short)(v0 & 0xffffu)); s0y += bf2f((unsigned short)(v0 >> 16));
      s1x += bf2f((unsigned short)(v1 & 0xffffu)); s1y += bf2f((unsigned short)(v1 >> 16));
      s2x += bf2f((unsigned short)(v2 & 0xffffu)); s2y += bf2f((unsigned short)(v2 >> 16));
      s3x += bf2f((unsigned short)(v3 & 0xffffu)); s3y += bf2f((unsigned short)(v3 >> 16));
    }
    for (; j < end; j += 2) {
      unsigned e = sq[j];
      unsigned v = xu[(e & 0xffffu) * 32 + l31];
      s0x += bf2f((unsigned short)(v & 0xffffu));
      s0y += bf2f((unsigned short)(v >> 16));
    }
    float sx = (s0x + s1x) + (s2x + s3x);
    float sy = (s0y + s1y) + (s2y + s3y);
    sx += __shfl_xor(sx, 32);
    sy += __shfl_xor(sy, 32);
    if (half == 0)
      ns_u[l31 * NSTR + n] = (unsigned)f2bf(sx) | ((unsigned)f2bf(sy) << 16);
  }
  __syncthreads();

  // fc: wave -> node-group g = wave&3 (16 nodes), out-group o = wave>>2 (2 nt)
  const int g = wave & 3;
  const int o = wave >> 2;
  const int l15 = lane & 15;
  const int quad = lane >> 4;
  const int node0 = nb + g * 16;

  int anode = node0 + l15;
  if (anode >= N_NODES) anode = N_NODES - 1;   // clamp; stores guarded
  const unsigned short* hx = xb + (size_t)anode * DFEAT;

  bf16x8 fa0 = *(const bf16x8*)(hx + quad * 8);        // k 0..31
  bf16x8 fa1 = *(const bf16x8*)(hx + 32 + quad * 8);   // k 32..63
  bf16x8 fa2, fa3;                                     // k 64..127 from ns_u
  {
    int m = g * 16 + l15;
    union { unsigned u[4]; bf16x8 v; } c2, c3;
#pragma unroll
    for (int i = 0; i < 4; ++i) {
      c2.u[i] = ns_u[(quad * 4 + i) * NSTR + m];
      c3.u[i] = ns_u[(16 + quad * 4 + i) * NSTR + m];
    }
    fa2 = c2.v;
    fa3 = c3.v;
  }

  f32x4 accr[2];
#pragma unroll
  for (int t = 0; t < 2; ++t) accr[t] = (f32x4){0.f, 0.f, 0.f, 0.f};

#pragma unroll
  for (int t = 0; t < 2; ++t) {
    int nt = o * 2 + t;
    const unsigned short* wr = Wb + (size_t)(nt * 16 + l15) * (2 * DFEAT) + quad * 8;
    bf16x8 b0 = *(const bf16x8*)(wr);
    bf16x8 b1 = *(const bf16x8*)(wr + 32);
    bf16x8 b2 = *(const bf16x8*)(wr + 64);
    bf16x8 b3 = *(const bf16x8*)(wr + 96);
    accr[t] = __builtin_amdgcn_mfma_f32_16x16x32_bf16(fa0, b0, accr[t], 0, 0, 0);
    accr[t] = __builtin_amdgcn_mfma_f32_16x16x32_bf16(fa1, b1, accr[t], 0, 0, 0);
    accr[t] = __builtin_amdgcn_mfma_f32_16x16x32_bf16(fa2, b2, accr[t], 0, 0, 0);
    accr[t] = __builtin_amdgcn_mfma_f32_16x16x32_bf16(fa3, b3, accr[t], 0, 0, 0);
  }

  // epilogue: D[m=quad*4+r][n=nt*16+l15]
#pragma unroll
  for (int t = 0; t < 2; ++t) {
    int nt = o * 2 + t;
    float bias = bv[nt * 16 + l15];
#pragma unroll
    for (int r = 0; r < 4; ++r) {
      int node = node0 + quad * 4 + r;
      if (node < N_NODES) {
        float v = accr[t][r] + bias;
        out[(size_t)node * HID + nt * 16 + l15] = v > 0.f ? v : 0.f;
      }
    }
  }
}

extern "C" void kernel_launch(void* const* d_in, const int* in_sizes, int n_in,
                              void* d_out, int out_size, void* d_ws, size_t ws_size,
                              hipStream_t stream) {
  const float* x = (const float*)d_in[0];
  const int* ei = (const int*)d_in[1];
  const float* W = (const float*)d_in[2];
  const float* b = (const float*)d_in[3];
  float* out = (float*)d_out;

  // workspace layout (~18 MB), 256B-aligned regions
  char* ws = (char*)d_ws;
  int* subcnt          = (int*)ws;            ws += 3328;                 // 800 ints
  int* pcnt            = (int*)ws;            ws += (size_t)EB_BLOCKS * NBKT * 4;
  unsigned int* coarse = (unsigned int*)ws;   ws += (size_t)NBKT * CAPB * 4;
  unsigned int* sub    = (unsigned int*)ws;   ws += (size_t)NSUB * CAP_S * 4;
  unsigned short* xb   = (unsigned short*)ws; ws += (size_t)N_NODES * DFEAT * 2;
  unsigned short* Wb   = (unsigned short*)ws; ws += (size_t)HID * 2 * DFEAT * 2;

  k_prep<<<XB_BLOCKS + WB_BLOCKS + EB_BLOCKS, 256, 0, stream>>>(
      x, W, ei, xb, Wb, subcnt, pcnt, coarse);
  k_refine<<<NBKT * NRCH, 256, 0, stream>>>(coarse, pcnt, subcnt, sub);
  k_gnn<<<(N_NODES + 63) / 64, 1024, 0, stream>>>(xb, Wb, subcnt, sub, b, out);
}

// Round 14
// 126.718 us; speedup vs baseline: 3.6017x; 1.0027x over previous
//
#include <hip/hip_runtime.h>

#define N_NODES 50000
#define N_EDGES 800000
#define DFEAT 64
#define HID 128
#define NBKT 782          // buckets of 64 nodes: bkt = dst>>6
#define NSEG 391          // edge blocks (2048 edges each); seg = block
#define SEGW 16           // words/segment: [count][15 entries] = 64B
#define CAP_S 1536        // per-block sorted queue: mean 1024, sigma 32
#define NSTR 66           // ns_u stride: write 2-way, frag read 2-way (free)

#define XB2 1563          // ceil(800000/512) x->bf16 blocks (512 thr)
#define WB2 8             // 4096/512 W->bf16 blocks
#define EB2 391           // edge blocks

typedef __bf16 bf16x8 __attribute__((ext_vector_type(8)));
typedef float f32x4 __attribute__((ext_vector_type(4)));

__device__ inline unsigned short f2bf(float f) {   // round-to-nearest-even
  unsigned u = __float_as_uint(f);
  return (unsigned short)((u + 0x7FFFu + ((u >> 16) & 1u)) >> 16);
}
__device__ inline float bf2f(unsigned short h) {
  return __uint_as_float(((unsigned)h) << 16);
}

// ---------- prep: bf16 cvt (x,W) + direct 64-node binning, count-embedded segs ----------
__global__ __launch_bounds__(512) void k_prep(const float* __restrict__ x,
                                              const float* __restrict__ W,
                                              const int* __restrict__ ei,
                                              unsigned short* __restrict__ xb,
                                              unsigned short* __restrict__ Wb,
                                              unsigned int* __restrict__ coarse) {
  int bid = blockIdx.x;
  const int tid = threadIdx.x;
  if (bid < XB2) {                            // x -> bf16
    int t = bid * 512 + tid;
    if (t < N_NODES * DFEAT / 4) {
      float4 v = *(const float4*)&x[t * 4];
      ushort4 o = {f2bf(v.x), f2bf(v.y), f2bf(v.z), f2bf(v.w)};
      *(ushort4*)&xb[t * 4] = o;
    }
    return;
  }
  bid -= XB2;
  if (bid < WB2) {                            // W -> bf16
    int t = bid * 512 + tid;
    float4 v = *(const float4*)&W[t * 4];
    ushort4 o = {f2bf(v.x), f2bf(v.y), f2bf(v.z), f2bf(v.w)};
    *(ushort4*)&Wb[t * 4] = o;
    return;
  }
  bid -= WB2;                                 // edge block = segment bid, 2048 edges
  __shared__ int lcnt[NBKT];
  for (int i = tid; i < NBKT; i += 512) lcnt[i] = 0;
  __syncthreads();

  int e0 = (bid * 512 + tid) * 4;
  if (e0 < N_EDGES) {                         // N_EDGES%4==0: all-or-nothing
    int4 s4 = *(const int4*)&ei[e0];
    int4 d4 = *(const int4*)&ei[N_EDGES + e0];
    int ss[4] = {s4.x, s4.y, s4.z, s4.w};
    int dd[4] = {d4.x, d4.y, d4.z, d4.w};
#pragma unroll
    for (int i = 0; i < 4; ++i) {
      int bkt = dd[i] >> 6;                   // 64-node bucket, no division
      int rank = atomicAdd(&lcnt[bkt], 1);
      if (rank < SEGW - 1)
        coarse[(size_t)bkt * (NSEG * SEGW) + bid * SEGW + 1 + rank] =
            ((unsigned)dd[i] << 16) | (unsigned)ss[i];
    }
  }
  __syncthreads();
  for (int i = tid; i < NBKT; i += 512) {     // embedded count word
    int c = lcnt[i];
    coarse[(size_t)i * (NSEG * SEGW) + bid * SEGW] =
        (unsigned)(c < SEGW - 1 ? c : SEGW - 1);
  }
}

// ---------- fused: scan bucket -> compact -> counting-sort -> gather -> MFMA fc ----------
__global__ __launch_bounds__(1024) void k_gnn(const unsigned short* __restrict__ xb,
                                              const unsigned short* __restrict__ Wb,
                                              const unsigned int* __restrict__ coarse,
                                              const float* __restrict__ bv,
                                              float* __restrict__ out) {
  __shared__ unsigned int q[CAP_S];
  __shared__ unsigned int sq[CAP_S];
  __shared__ unsigned int ns_u[32 * NSTR];   // [feat-pair][node], bf16x2 packed
  __shared__ int scnt[NSEG];
  __shared__ int lcnt[64];
  __shared__ int lbase[65];
  __shared__ int qn;

  const int tid = threadIdx.x;
  const int b = blockIdx.x;
  const int nb = b * 64;
  const unsigned int* base = coarse + (size_t)b * (NSEG * SEGW);

  if (tid < 64) lcnt[tid] = 0;
  if (tid == 0) qn = 0;
  for (int i = tid; i < NSEG; i += 1024) {
    int c = (int)base[i * SEGW];
    scnt[i] = c < SEGW - 1 ? c : SEGW - 1;
  }
  __syncthreads();

  // scan all segments (contiguous 25KB), compact valid entries into q
  const int NU4 = NSEG * SEGW / 4;           // 1564 uint4
  for (int i = tid; i < NU4; i += 1024) {
    uint4 w = ((const uint4*)base)[i];
    int seg = i >> 2;
    int wi = (i & 3) * 4;                    // word index of w.x within segment
    int cnt = scnt[seg];
    unsigned e[4] = {w.x, w.y, w.z, w.w};
#pragma unroll
    for (int k = 0; k < 4; ++k) {
      int widx = wi + k;                     // entries live at widx 1..cnt
      if (widx >= 1 && widx <= cnt) {
        int pos = atomicAdd(&qn, 1);
        if (pos < CAP_S) q[pos] = e[k] & 0x003fffffu;   // (dst&63)<<16 | src
      }
    }
  }
  __syncthreads();

  int cnt = qn < CAP_S ? qn : CAP_S;

  // counting sort by node (int LDS atomics only) — R13-proven
  int myrank[2], myidx[2], nloc = 0;
  for (int i = tid; i < cnt; i += 1024) {
    int rel = (int)(q[i] >> 16);
    myrank[nloc] = atomicAdd(&lcnt[rel], 1);
    myidx[nloc] = i;
    ++nloc;
  }
  __syncthreads();
  if (tid < 64) {
    int v = lcnt[tid];
    int inc = v;
#pragma unroll
    for (int o = 1; o < 64; o <<= 1) {
      int u = __shfl_up(inc, o);
      if (tid >= o) inc += u;
    }
    lbase[tid] = inc - v;
    if (tid == 63) lbase[64] = inc;
  }
  __syncthreads();
  for (int k = 0; k < nloc; ++k) {
    unsigned e = q[myidx[k]];
    sq[lbase[e >> 16] + myrank[k]] = e;
  }
  __syncthreads();

  // gather: wave w -> nodes w*4..w*4+3; lane = (entry-slot, uint2-chunk)
  const int wave = tid >> 6;
  const int lane = tid & 63;
  const int eslot = lane >> 4;    // 4 entries per wave-load round
  const int c = lane & 15;        // uint2 chunk = features 4c..4c+3
  const uint2* xu2 = (const uint2*)xb;

#pragma unroll
  for (int i2 = 0; i2 < 4; ++i2) {
    int n = wave * 4 + i2;
    int beg = lbase[n], end = lbase[n + 1];
    float f0 = 0.f, f1 = 0.f, f2 = 0.f, f3 = 0.f;
    float g0 = 0.f, g1 = 0.f, g2 = 0.f, g3 = 0.f;
    int j = beg + eslot;
    for (; j + 4 < end; j += 8) {            // ILP-2: 8 entries per iter
      unsigned e0 = sq[j], e1 = sq[j + 4];
      uint2 v0 = xu2[(e0 & 0xffffu) * 16 + c];
      uint2 v1 = xu2[(e1 & 0xffffu) * 16 + c];
      f0 += bf2f((unsigned short)(v0.x & 0xffffu)); f1 += bf2f((unsigned short)(v0.x >> 16));
      f2 += bf2f((unsigned short)(v0.y & 0xffffu)); f3 += bf2f((unsigned short)(v0.y >> 16));
      g0 += bf2f((unsigned short)(v1.x & 0xffffu)); g1 += bf2f((unsigned short)(v1.x >> 16));
      g2 += bf2f((unsigned short)(v1.y & 0xffffu)); g3 += bf2f((unsigned short)(v1.y >> 16));
    }
    for (; j < end; j += 4) {
      unsigned e = sq[j];
      uint2 v = xu2[(e & 0xffffu) * 16 + c];
      f0 += bf2f((unsigned short)(v.x & 0xffffu)); f1 += bf2f((unsigned short)(v.x >> 16));
      f2 += bf2f((unsigned short)(v.y & 0xffffu)); f3 += bf2f((unsigned short)(v.y >> 16));
    }
    f0 += g0; f1 += g1; f2 += g2; f3 += g3;
    f0 += __shfl_xor(f0, 16); f0 += __shfl_xor(f0, 32);
    f1 += __shfl_xor(f1, 16); f1 += __shfl_xor(f1, 32);
    f2 += __shfl_xor(f2, 16); f2 += __shfl_xor(f2, 32);
    f3 += __shfl_xor(f3, 16); f3 += __shfl_xor(f3, 32);
    if (eslot == 0) {
      ns_u[(2 * c) * NSTR + n] = (unsigned)f2bf(f0) | ((unsigned)f2bf(f1) << 16);
      ns_u[(2 * c + 1) * NSTR + n] = (unsigned)f2bf(f2) | ((unsigned)f2bf(f3) << 16);
    }
  }
  __syncthreads();

  // fc: wave -> node-group g = wave&3 (16 nodes), out-group o = wave>>2 (2 nt)
  const int g = wave & 3;
  const int o = wave >> 2;
  const int l15 = lane & 15;
  const int quad = lane >> 4;
  const int node0 = nb + g * 16;

  int anode = node0 + l15;
  if (anode >= N_NODES) anode = N_NODES - 1;   // clamp; stores guarded
  const unsigned short* hx = xb + (size_t)anode * DFEAT;

  bf16x8 fa0 = *(const bf16x8*)(hx + quad * 8);        // k 0..31
  bf16x8 fa1 = *(const bf16x8*)(hx + 32 + quad * 8);   // k 32..63
  bf16x8 fa2, fa3;                                     // k 64..127 from ns_u
  {
    int m = g * 16 + l15;
    union { unsigned u[4]; bf16x8 v; } c2, c3;
#pragma unroll
    for (int i = 0; i < 4; ++i) {
      c2.u[i] = ns_u[(quad * 4 + i) * NSTR + m];
      c3.u[i] = ns_u[(16 + quad * 4 + i) * NSTR + m];
    }
    fa2 = c2.v;
    fa3 = c3.v;
  }

  f32x4 accr[2];
#pragma unroll
  for (int t = 0; t < 2; ++t) accr[t] = (f32x4){0.f, 0.f, 0.f, 0.f};

#pragma unroll
  for (int t = 0; t < 2; ++t) {
    int nt = o * 2 + t;
    const unsigned short* wr = Wb + (size_t)(nt * 16 + l15) * (2 * DFEAT) + quad * 8;
    bf16x8 b0 = *(const bf16x8*)(wr);
    bf16x8 b1 = *(const bf16x8*)(wr + 32);
    bf16x8 b2 = *(const bf16x8*)(wr + 64);
    bf16x8 b3 = *(const bf16x8*)(wr + 96);
    accr[t] = __builtin_amdgcn_mfma_f32_16x16x32_bf16(fa0, b0, accr[t], 0, 0, 0);
    accr[t] = __builtin_amdgcn_mfma_f32_16x16x32_bf16(fa1, b1, accr[t], 0, 0, 0);
    accr[t] = __builtin_amdgcn_mfma_f32_16x16x32_bf16(fa2, b2, accr[t], 0, 0, 0);
    accr[t] = __builtin_amdgcn_mfma_f32_16x16x32_bf16(fa3, b3, accr[t], 0, 0, 0);
  }

  // epilogue: D[m=quad*4+r][n=nt*16+l15]
#pragma unroll
  for (int t = 0; t < 2; ++t) {
    int nt = o * 2 + t;
    float bias = bv[nt * 16 + l15];
#pragma unroll
    for (int r = 0; r < 4; ++r) {
      int node = node0 + quad * 4 + r;
      if (node < N_NODES) {
        float v = accr[t][r] + bias;
        out[(size_t)node * HID + nt * 16 + l15] = v > 0.f ? v : 0.f;
      }
    }
  }
}

extern "C" void kernel_launch(void* const* d_in, const int* in_sizes, int n_in,
                              void* d_out, int out_size, void* d_ws, size_t ws_size,
                              hipStream_t stream) {
  const float* x = (const float*)d_in[0];
  const int* ei = (const int*)d_in[1];
  const float* W = (const float*)d_in[2];
  const float* b = (const float*)d_in[3];
  float* out = (float*)d_out;

  // workspace layout (~26 MB), 256B-aligned
  char* ws = (char*)d_ws;
  unsigned int* coarse = (unsigned int*)ws;   ws += (size_t)NBKT * NSEG * SEGW * 4;
  unsigned short* xb   = (unsigned short*)ws; ws += (size_t)N_NODES * DFEAT * 2;
  unsigned short* Wb   = (unsigned short*)ws; ws += (size_t)HID * 2 * DFEAT * 2;

  k_prep<<<XB2 + WB2 + EB2, 512, 0, stream>>>(x, W, ei, xb, Wb, coarse);
  k_gnn<<<NBKT, 1024, 0, stream>>>(xb, Wb, coarse, b, out);
}